// Round 5
// baseline (1295.888 us; speedup 1.0000x reference)
//
#include <hip/hip_runtime.h>
#include <math.h>

#define Bn 2
#define Nn 50000
#define En 262144
#define Dn 256
#define Hn 1024
#define RTOT (Bn*Nn)

typedef short bf16x8 __attribute__((ext_vector_type(8)));
typedef float f32x4 __attribute__((ext_vector_type(4)));

__device__ __forceinline__ short f2b(float f) {
  unsigned u = __float_as_uint(f);
  u = u + 0x7fffu + ((u >> 16) & 1u);   // RNE to bf16
  return (short)(u >> 16);
}

// 3-term A&S 7.1.25 erf, |err|<=2.5e-5 (plenty for bf16 output)
__device__ __forceinline__ float gelu_f(float v) {
  float x = fabsf(v) * 0.70710678118654752f;
  float t = __builtin_amdgcn_rcpf(1.0f + 0.47047f * x);
  float p = t*(0.3480242f + t*(-0.0958798f + t*0.7478556f));
  float er = 1.0f - p * __expf(-x*x);
  er = copysignf(er, v);
  return 0.5f * v * (1.0f + er);
}

__device__ __forceinline__ void gl16(const void* g, void* l) {
  __builtin_amdgcn_global_load_lds(
      (const __attribute__((address_space(1))) unsigned int*)g,
      (__attribute__((address_space(3))) unsigned int*)l, 16, 0, 0);
}

// ---------- weight transpose + f32->bf16 ----------
__global__ void __launch_bounds__(256) wconv(
    const float* __restrict__ relw, const float* __restrict__ w1,
    const float* __restrict__ w2, short* __restrict__ relwT,
    short* __restrict__ w1T, short* __restrict__ w2T) {
  int tid = blockIdx.x * 256 + threadIdx.x;
  if (tid < Dn*Dn) { int c = tid >> 8, k = tid & 255; relwT[tid] = f2b(relw[k*Dn + c]); }
  int t1 = tid - Dn*Dn;
  if (t1 >= 0 && t1 < Dn*Hn) { int c = t1 >> 8, k = t1 & 255; w1T[t1] = f2b(w1[k*Hn + c]); }
  int t2 = tid - Dn*Dn - Dn*Hn;
  if (t2 >= 0 && t2 < Hn*Dn) { int c = t2 >> 10, k = t2 & 1023; w2T[t2] = f2b(w2[k*Dn + c]); }
}

// ---------- CSR build ----------
__global__ void __launch_bounds__(256) histk(const int* __restrict__ ei, int* __restrict__ cnt) {
  int tid = blockIdx.x * 256 + threadIdx.x;
  if (tid >= Bn*En) return;
  int b = tid / En;
  int tgt = ei[tid*2 + 1];
  atomicAdd(&cnt[b*Nn + tgt], 1);
}

// parallel offsets: per-wave prefix + one atomic per wave (order-independent)
__global__ void __launch_bounds__(256) offsk(const int* __restrict__ cnt,
                                             int* __restrict__ offs, int* __restrict__ gtot) {
  int i = blockIdx.x * 256 + threadIdx.x;
  int lane = threadIdx.x & 63;
  int v = (i < RTOT) ? cnt[i] : 0;
  int s = v;
#pragma unroll
  for (int d = 1; d < 64; d <<= 1) {
    int t = __shfl_up(s, d, 64);
    if (lane >= d) s += t;
  }
  int base = 0;
  if (lane == 63) base = atomicAdd(gtot, s);
  base = __shfl(base, 63, 64);
  if (i < RTOT) offs[i] = base + s - v;
}

__global__ void __launch_bounds__(256) fillk(const int* __restrict__ ei, const int* __restrict__ offs,
                                             int* __restrict__ cursor, int* __restrict__ eids) {
  int tid = blockIdx.x * 256 + threadIdx.x;
  if (tid >= Bn*En) return;
  int b = tid / En, e = tid - b*En;
  int tgt = ei[tid*2 + 1];
  int node = b*Nn + tgt;
  int pos = atomicAdd(&cursor[node], 1);
  eids[offs[node] + pos] = e;
}

// ---------- aggregation ----------
__global__ void __launch_bounds__(256) aggk(
    const float* __restrict__ nodef, const float* __restrict__ erel,
    const float* __restrict__ emask, const int* __restrict__ ei,
    const int* __restrict__ offs, const int* __restrict__ cnt,
    const int* __restrict__ eids,
    float* __restrict__ sumrel, float* __restrict__ cntf, float* __restrict__ outsrc) {
  int w = (blockIdx.x * 256 + threadIdx.x) >> 6;
  int lane = threadIdx.x & 63;
  if (w >= RTOT) return;
  int b = w / Nn;
  const size_t ebase = (size_t)b * En;
  const size_t nbase = (size_t)b * Nn;
  int s0 = offs[w], s1 = s0 + cnt[w];
  float r0=0,r1=0,r2=0,r3=0, a0=0,a1=0,a2=0,a3=0, cf=0;
  for (int base = s0; base < s1; base += 64) {
    int k = s1 - base; if (k > 64) k = 64;
    int e = 0, sr = 0; float m = 0.f;
    if (lane < k) {
      e  = eids[base + lane];
      sr = ei[(ebase + e)*2];
      m  = emask[ebase + e];
    }
    int e0 = __shfl(e, 0), sr0 = __shfl(sr, 0);
    float m0 = __shfl(m, 0);
    float4 rvA = *(const float4*)(erel  + (ebase + e0)*Dn + lane*4);
    float4 nvA = *(const float4*)(nodef + (nbase + sr0)*Dn + lane*4);
    for (int j = 0; j < k; j++) {
      float4 rvB = make_float4(0,0,0,0), nvB = make_float4(0,0,0,0);
      float m1 = 0.f;
      if (j + 1 < k) {
        int e1 = __shfl(e, j+1), sr1 = __shfl(sr, j+1);
        m1 = __shfl(m, j+1);
        rvB = *(const float4*)(erel  + (ebase + e1)*Dn + lane*4);
        nvB = *(const float4*)(nodef + (nbase + sr1)*Dn + lane*4);
      }
      r0 += rvA.x*m0; r1 += rvA.y*m0; r2 += rvA.z*m0; r3 += rvA.w*m0;
      a0 += nvA.x*m0; a1 += nvA.y*m0; a2 += nvA.z*m0; a3 += nvA.w*m0;
      cf += m0;
      rvA = rvB; nvA = nvB; m0 = m1;
    }
  }
  size_t ob = (size_t)w*Dn + lane*4;
  *(float4*)(sumrel + ob) = make_float4(r0,r1,r2,r3);
  *(float4*)(outsrc + ob) = make_float4(a0,a1,a2,a3);
  if (lane == 0) cntf[w] = cf;
}

// ---------- helpers for relln ----------
template<int MR>
__device__ __forceinline__ void stageX(const float* __restrict__ src, char* lds, int row0, int tid) {
#pragma unroll
  for (int i = 0; i < MR*4; i++) {
    int flat = tid + 256*i;
    int r = flat >> 6, c4 = flat & 63;
    float4 v = *(const float4*)(src + (size_t)(row0 + r)*Dn + c4*4);
    short4 s; s.x=f2b(v.x); s.y=f2b(v.y); s.z=f2b(v.z); s.w=f2b(v.w);
    int byte = r*512 + ((c4*8) ^ ((r & 7) << 4));
    *(short4*)(lds + byte) = s;
  }
}

__device__ __forceinline__ bf16x8 ldsA(const char* lds, int r, int kb) {
  int byte = r*512 + (((kb)*2) ^ ((r & 7) << 4));
  return *(const bf16x8*)(lds + byte);
}

template<int MR>
__device__ __forceinline__ void ln_write(f32x4 (&acc)[MR][4], float* red,
    const float* __restrict__ sc, const float* __restrict__ bi,
    float* __restrict__ out, int row0, int lane, int wv) {
  constexpr int R = MR*16;
  int l15 = lane & 15, l4 = lane >> 4;
  int cols[4]; float sc_c[4], bi_c[4];
#pragma unroll
  for (int n = 0; n < 4; n++) {
    cols[n] = wv*64 + n*16 + l15;
    sc_c[n] = sc[cols[n]]; bi_c[n] = bi[cols[n]];
  }
  float s1[MR][4], s2[MR][4];
#pragma unroll
  for (int m = 0; m < MR; m++)
#pragma unroll
    for (int g = 0; g < 4; g++) {
      float a = 0.f, b = 0.f;
#pragma unroll
      for (int n = 0; n < 4; n++) { float p = acc[m][n][g]; a += p; b += p*p; }
#pragma unroll
      for (int d = 1; d < 16; d <<= 1) { a += __shfl_xor(a, d, 16); b += __shfl_xor(b, d, 16); }
      s1[m][g] = a; s2[m][g] = b;
    }
  if (l15 == 0) {
#pragma unroll
    for (int m = 0; m < MR; m++)
#pragma unroll
      for (int g = 0; g < 4; g++) {
        int r = m*16 + l4*4 + g;
        red[(wv*R + r)*2]     = s1[m][g];
        red[(wv*R + r)*2 + 1] = s2[m][g];
      }
  }
  __syncthreads();
#pragma unroll
  for (int m = 0; m < MR; m++)
#pragma unroll
    for (int g = 0; g < 4; g++) {
      int r = m*16 + l4*4 + g; int rg = row0 + r;
      float t1 = 0.f, t2 = 0.f;
#pragma unroll
      for (int u = 0; u < 4; u++) { t1 += red[(u*R + r)*2]; t2 += red[(u*R + r)*2 + 1]; }
      float mean = t1 * (1.0f/Dn);
      float var  = t2 * (1.0f/Dn) - mean*mean;
      float rstd = rsqrtf(var + 1e-5f);
#pragma unroll
      for (int n = 0; n < 4; n++)
        out[(size_t)rg*Dn + cols[n]] = (acc[m][n][g] - mean)*rstd*sc_c[n] + bi_c[n];
    }
}

// ---------- K3: relln ----------
__global__ void __launch_bounds__(256, 4) relln(
    const float* __restrict__ sumrel, const short* __restrict__ relwT,
    const float* __restrict__ relb, const float* __restrict__ nodef,
    const float* __restrict__ cntf, const float* __restrict__ ns,
    const float* __restrict__ nb, float* __restrict__ xout) {
  constexpr int MR = 2;
  __shared__ __align__(16) char lds[16384 + 1024];
  float* red = (float*)(lds + 16384);
  int tid = threadIdx.x;
  int lane = tid & 63, wv = tid >> 6;
  int l15 = lane & 15, l4 = lane >> 4;
  int row0 = blockIdx.x * (MR*16);
  stageX<MR>(sumrel, lds, row0, tid);
  __syncthreads();
  f32x4 acc[MR][4] = {};
#pragma unroll
  for (int ks = 0; ks < 8; ks++) {
    bf16x8 af[MR], bfr[4];
#pragma unroll
    for (int m = 0; m < MR; m++) af[m] = ldsA(lds, m*16 + l15, ks*32 + l4*8);
#pragma unroll
    for (int n = 0; n < 4; n++) {
      int col = wv*64 + n*16 + l15;
      bfr[n] = *(const bf16x8*)(relwT + col*Dn + ks*32 + l4*8);
    }
#pragma unroll
    for (int m = 0; m < MR; m++)
#pragma unroll
      for (int n = 0; n < 4; n++)
        acc[m][n] = __builtin_amdgcn_mfma_f32_16x16x32_bf16(af[m], bfr[n], acc[m][n], 0, 0, 0);
  }
  int cols[4]; float rb_c[4];
#pragma unroll
  for (int n = 0; n < 4; n++) { cols[n] = wv*64 + n*16 + l15; rb_c[n] = relb[cols[n]]; }
#pragma unroll
  for (int m = 0; m < MR; m++)
#pragma unroll
    for (int g = 0; g < 4; g++) {
      int r = m*16 + l4*4 + g; int rg = row0 + r;
      float cf  = cntf[rg];
      float inv = 1.0f / fmaxf(cf, 1.0f);
#pragma unroll
      for (int n = 0; n < 4; n++) {
        float ssrc = xout[(size_t)rg*Dn + cols[n]];
        float nfv  = nodef[(size_t)rg*Dn + cols[n]];
        float aggv = (ssrc + acc[m][n][g] + cf*rb_c[n]) * inv;
        acc[m][n][g] = nfv + aggv;
      }
    }
  ln_write<MR>(acc, red, ns, nb, xout, row0, lane, wv);
}

// ---------- K4: FFN v5 — X in regs, 80KB LDS (2 blocks/CU), plain barriers ----------
#define FBM 128
// LDS: W1c [0,32K), W2c [32K,64K), Hs [64K,80K); red aliases W1c post-loop

__global__ void __launch_bounds__(512, 4) ffnk(
    const short* __restrict__ w1T, const float* __restrict__ b1,
    const short* __restrict__ w2T, const float* __restrict__ b2,
    const float* __restrict__ fs, const float* __restrict__ fb,
    float* __restrict__ xio) {
  __shared__ __align__(16) char lds[81920];
  char* W1c = lds;
  char* W2c = lds + 32768;
  char* Hs  = lds + 65536;
  float* red = (float*)lds;            // alias on W1c (used only after loop)

  int tid = threadIdx.x;
  int lane = tid & 63, wv = tid >> 6;
  int l15 = lane & 15, l4 = lane >> 4;
  int wm = wv >> 2, wn = wv & 3;       // 2 x 4 wave grid
  int row0 = blockIdx.x * FBM;
  const char* w1b = (const char*)w1T;
  const char* w2b = (const char*)w2T;

  // ---- X fragments straight to registers (B-operand layout), rows clamped ----
  bf16x8 xf[4][8];
#pragma unroll
  for (int mf = 0; mf < 4; mf++) {
    int rg = row0 + wm*64 + mf*16 + l15;
    if (rg > RTOT - 1) rg = RTOT - 1;
    const float* p = xio + (size_t)rg*Dn;
#pragma unroll
    for (int ks = 0; ks < 8; ks++) {
      float4 v0 = *(const float4*)(p + ks*32 + l4*8);
      float4 v1 = *(const float4*)(p + ks*32 + l4*8 + 4);
      bf16x8 r;
      r[0]=f2b(v0.x); r[1]=f2b(v0.y); r[2]=f2b(v0.z); r[3]=f2b(v0.w);
      r[4]=f2b(v1.x); r[5]=f2b(v1.y); r[6]=f2b(v1.z); r[7]=f2b(v1.w);
      xf[mf][ks] = r;
    }
  }

  f32x4 acc2[4][4] = {};
  int cl = wn*16 + l15;

#pragma unroll 1
  for (int hc = 0; hc < 16; hc++) {
    __syncthreads();                    // prev iter's readers of W1c/W2c/Hs done
    // ---- stage W1 chunk (64 cols x 256 k = 32KB) + W2 chunk (256 cols x 64 k = 32KB) ----
#pragma unroll
    for (int i = 0; i < 4; i++) {
      int o = (wv*4 + i)*1024 + lane*16;
      int r = o >> 9, byte = o & 511;
      gl16(w1b + (((size_t)(hc*64 + r)) << 9) + (byte ^ ((r & 7) << 4)), W1c + (wv*4 + i)*1024);
    }
#pragma unroll
    for (int i = 0; i < 4; i++) {
      int o = (wv*4 + i)*1024 + lane*16;
      int r = o >> 7, byte = o & 127;
      gl16(w2b + (((size_t)r) << 11) + (hc << 7) + (byte ^ ((r & 7) << 4)), W2c + (wv*4 + i)*1024);
    }
    __syncthreads();                    // staging visible (barrier drains vmcnt)

    // ---- GEMM1 (swapped): lane=X-row, acc regs=w1 cols ----
    f32x4 acc1[4] = {};
#pragma unroll
    for (int ks = 0; ks < 8; ks++) {
      bf16x8 w1f = *(const bf16x8*)(W1c + cl*512 + (((ks*32 + l4*8)*2) ^ ((cl & 7) << 4)));
#pragma unroll
      for (int mf = 0; mf < 4; mf++)
        acc1[mf] = __builtin_amdgcn_mfma_f32_16x16x32_bf16(w1f, xf[mf][ks], acc1[mf], 0, 0, 0);
    }

    // ---- bias + gelu -> Hs (short4, conflict-free) ----
    float4 b1v = *(const float4*)(b1 + hc*64 + wn*16 + l4*4);
#pragma unroll
    for (int mf = 0; mf < 4; mf++) {
      short4 s;
      s.x = f2b(gelu_f(acc1[mf][0] + b1v.x));
      s.y = f2b(gelu_f(acc1[mf][1] + b1v.y));
      s.z = f2b(gelu_f(acc1[mf][2] + b1v.z));
      s.w = f2b(gelu_f(acc1[mf][3] + b1v.w));
      int R = wm*64 + mf*16 + l15;
      *(short4*)(Hs + R*128 + ((wn*32 + l4*8) ^ ((R & 7) << 4))) = s;
    }
    __syncthreads();                    // Hs ready

    // ---- GEMM2: acc2 += H(128x64) @ W2chunk(64x256) ----
#pragma unroll
    for (int ksl = 0; ksl < 2; ksl++) {
      bf16x8 ah[4], bw[4];
#pragma unroll
      for (int mf = 0; mf < 4; mf++) {
        int rr = wm*64 + mf*16 + l15;
        ah[mf] = *(const bf16x8*)(Hs + rr*128 + (((ksl*32 + l4*8)*2) ^ ((rr & 7) << 4)));
      }
#pragma unroll
      for (int nf = 0; nf < 4; nf++) {
        int oc = wn*64 + nf*16 + l15;
        bw[nf] = *(const bf16x8*)(W2c + oc*128 + (((ksl*32 + l4*8)*2) ^ ((oc & 7) << 4)));
      }
#pragma unroll
      for (int mf = 0; mf < 4; mf++)
#pragma unroll
        for (int nf = 0; nf < 4; nf++)
          acc2[mf][nf] = __builtin_amdgcn_mfma_f32_16x16x32_bf16(ah[mf], bw[nf], acc2[mf][nf], 0, 0, 0);
    }
  }
  __syncthreads();                      // all GEMM2 reads done; red (on W1c) free

  // ---- epilogue: residual (re-read xio) + b2, LayerNorm ----
  float b2c[4], fsc[4], fbc[4];
#pragma unroll
  for (int nf = 0; nf < 4; nf++) {
    int col = wn*64 + nf*16 + l15;
    b2c[nf] = b2[col]; fsc[nf] = fs[col]; fbc[nf] = fb[col];
  }
#pragma unroll
  for (int mf = 0; mf < 4; mf++)
#pragma unroll
    for (int g = 0; g < 4; g++) {
      int R = wm*64 + mf*16 + l4*4 + g;
      int rg = row0 + R;
      bool ok = rg < RTOT;
      float a = 0.f, q = 0.f;
#pragma unroll
      for (int nf = 0; nf < 4; nf++) {
        int col = wn*64 + nf*16 + l15;
        float xv = ok ? xio[(size_t)rg*Dn + col] : 0.f;
        float vv = xv + acc2[mf][nf][g] + b2c[nf];
        acc2[mf][nf][g] = vv;
        a += vv; q += vv*vv;
      }
#pragma unroll
      for (int d = 1; d < 16; d <<= 1) { a += __shfl_xor(a, d, 16); q += __shfl_xor(q, d, 16); }
      if (l15 == 0) {
        red[(wn*FBM + R)*2]     = a;
        red[(wn*FBM + R)*2 + 1] = q;
      }
    }
  __syncthreads();
#pragma unroll
  for (int mf = 0; mf < 4; mf++)
#pragma unroll
    for (int g = 0; g < 4; g++) {
      int R = wm*64 + mf*16 + l4*4 + g;
      int rg = row0 + R;
      if (rg >= RTOT) continue;
      float t1 = 0.f, t2 = 0.f;
#pragma unroll
      for (int u = 0; u < 4; u++) { t1 += red[(u*FBM + R)*2]; t2 += red[(u*FBM + R)*2 + 1]; }
      float mean = t1 * (1.0f/Dn);
      float var  = t2 * (1.0f/Dn) - mean*mean;
      float rstd = rsqrtf(var + 1e-5f);
#pragma unroll
      for (int nf = 0; nf < 4; nf++) {
        int col = wn*64 + nf*16 + l15;
        xio[(size_t)rg*Dn + col] = (acc2[mf][nf][g] - mean)*rstd*fsc[nf] + fbc[nf];
      }
    }
}

// ---------- host ----------
extern "C" void kernel_launch(void* const* d_in, const int* in_sizes, int n_in,
                              void* d_out, int out_size, void* d_ws, size_t ws_size,
                              hipStream_t stream) {
  const float* nodef = (const float*)d_in[0];
  const float* erel  = (const float*)d_in[1];
  const float* emask = (const float*)d_in[2];
  const float* relw  = (const float*)d_in[3];
  const float* relb  = (const float*)d_in[4];
  const float* ns    = (const float*)d_in[5];
  const float* nb    = (const float*)d_in[6];
  const float* w1    = (const float*)d_in[7];
  const float* b1    = (const float*)d_in[8];
  const float* w2    = (const float*)d_in[9];
  const float* b2    = (const float*)d_in[10];
  const float* fs    = (const float*)d_in[11];
  const float* fb    = (const float*)d_in[12];
  const int*   ei    = (const int*)d_in[13];
  float* out = (float*)d_out;
  char* ws = (char*)d_ws;

  constexpr size_t SZ_SUMREL = (size_t)RTOT * Dn * 4;
  constexpr size_t O_CNT  = SZ_SUMREL;
  constexpr size_t O_CUR  = O_CNT + (size_t)RTOT*4;
  constexpr size_t O_OFF  = O_CUR + (size_t)RTOT*4;
  constexpr size_t O_EID  = O_OFF + ((size_t)(RTOT+1)*4 + 124);
  constexpr size_t O_CNTF = O_EID + (size_t)Bn*En*4;
  constexpr size_t O_RWT  = O_CNTF + (size_t)RTOT*4;
  constexpr size_t O_W1T  = O_RWT + (size_t)Dn*Dn*2;
  constexpr size_t O_W2T  = O_W1T + (size_t)Dn*Hn*2;
  constexpr size_t WS_NEED = O_W2T + (size_t)Hn*Dn*2;
  if (ws_size < WS_NEED) return;

  float* sumrel = (float*)(ws);
  int*   cnt    = (int*)(ws + O_CNT);
  int*   cursor = (int*)(ws + O_CUR);
  int*   offs   = (int*)(ws + O_OFF);
  int*   eids   = (int*)(ws + O_EID);
  float* cntf   = (float*)(ws + O_CNTF);
  short* relwT  = (short*)(ws + O_RWT);
  short* w1T    = (short*)(ws + O_W1T);
  short* w2T    = (short*)(ws + O_W2T);
  int*   gtot   = offs + RTOT;          // zeroed by the memset below

  // zero cnt + cursor + offs(+gtot)
  hipMemsetAsync(ws + O_CNT, 0, O_EID - O_CNT, stream);

  wconv<<<(Dn*Dn + Dn*Hn + Hn*Dn) / 256, 256, 0, stream>>>(relw, w1, w2, relwT, w1T, w2T);
  histk<<<(Bn*En) / 256, 256, 0, stream>>>(ei, cnt);
  offsk<<<(RTOT + 255) / 256, 256, 0, stream>>>(cnt, offs, gtot);
  fillk<<<(Bn*En) / 256, 256, 0, stream>>>(ei, offs, cursor, eids);
  aggk<<<(RTOT + 3) / 4, 256, 0, stream>>>(nodef, erel, emask, ei, offs, cnt, eids, sumrel, cntf, out);
  relln<<<RTOT / 32, 256, 0, stream>>>(sumrel, relwT, relb, nodef, cntf, ns, nb, out);
  ffnk<<<(RTOT + FBM - 1) / FBM, 512, 0, stream>>>(w1T, b1, w2T, b2, fs, fb, out);
}

// Round 6
// 814.812 us; speedup vs baseline: 1.5904x; 1.5904x over previous
//
#include <hip/hip_runtime.h>
#include <math.h>

#define Bn 2
#define Nn 50000
#define En 262144
#define Dn 256
#define Hn 1024
#define RTOT (Bn*Nn)

typedef short bf16x8 __attribute__((ext_vector_type(8)));
typedef float f32x4 __attribute__((ext_vector_type(4)));

__device__ __forceinline__ short f2b(float f) {
  unsigned u = __float_as_uint(f);
  u = u + 0x7fffu + ((u >> 16) & 1u);   // RNE to bf16
  return (short)(u >> 16);
}

// 3-term A&S 7.1.25 erf, |err|<=2.5e-5 (plenty for bf16 output)
__device__ __forceinline__ float gelu_f(float v) {
  float x = fabsf(v) * 0.70710678118654752f;
  float t = __builtin_amdgcn_rcpf(1.0f + 0.47047f * x);
  float p = t*(0.3480242f + t*(-0.0958798f + t*0.7478556f));
  float er = 1.0f - p * __expf(-x*x);
  er = copysignf(er, v);
  return 0.5f * v * (1.0f + er);
}

// ---------- weight transpose + f32->bf16 ----------
__global__ void __launch_bounds__(256) wconv(
    const float* __restrict__ relw, const float* __restrict__ w1,
    const float* __restrict__ w2, short* __restrict__ relwT,
    short* __restrict__ w1T, short* __restrict__ w2T) {
  int tid = blockIdx.x * 256 + threadIdx.x;
  if (tid < Dn*Dn) { int c = tid >> 8, k = tid & 255; relwT[tid] = f2b(relw[k*Dn + c]); }
  int t1 = tid - Dn*Dn;
  if (t1 >= 0 && t1 < Dn*Hn) { int c = t1 >> 8, k = t1 & 255; w1T[t1] = f2b(w1[k*Hn + c]); }
  int t2 = tid - Dn*Dn - Dn*Hn;
  if (t2 >= 0 && t2 < Hn*Dn) { int c = t2 >> 10, k = t2 & 1023; w2T[t2] = f2b(w2[k*Dn + c]); }
}

// ---------- CSR build ----------
__global__ void __launch_bounds__(256) histk(const int* __restrict__ ei, int* __restrict__ cnt) {
  int tid = blockIdx.x * 256 + threadIdx.x;
  if (tid >= Bn*En) return;
  int b = tid / En;
  int tgt = ei[tid*2 + 1];
  atomicAdd(&cnt[b*Nn + tgt], 1);
}

// parallel offsets: per-wave prefix + one atomic per wave (order-independent)
__global__ void __launch_bounds__(256) offsk(const int* __restrict__ cnt,
                                             int* __restrict__ offs, int* __restrict__ gtot) {
  int i = blockIdx.x * 256 + threadIdx.x;
  int lane = threadIdx.x & 63;
  int v = (i < RTOT) ? cnt[i] : 0;
  int s = v;
#pragma unroll
  for (int d = 1; d < 64; d <<= 1) {
    int t = __shfl_up(s, d, 64);
    if (lane >= d) s += t;
  }
  int base = 0;
  if (lane == 63) base = atomicAdd(gtot, s);
  base = __shfl(base, 63, 64);
  if (i < RTOT) offs[i] = base + s - v;
}

__global__ void __launch_bounds__(256) fillk(const int* __restrict__ ei, const int* __restrict__ offs,
                                             int* __restrict__ cursor, int* __restrict__ eids) {
  int tid = blockIdx.x * 256 + threadIdx.x;
  if (tid >= Bn*En) return;
  int b = tid / En, e = tid - b*En;
  int tgt = ei[tid*2 + 1];
  int node = b*Nn + tgt;
  int pos = atomicAdd(&cursor[node], 1);
  eids[offs[node] + pos] = e;
}

// ---------- aggregation ----------
__global__ void __launch_bounds__(256) aggk(
    const float* __restrict__ nodef, const float* __restrict__ erel,
    const float* __restrict__ emask, const int* __restrict__ ei,
    const int* __restrict__ offs, const int* __restrict__ cnt,
    const int* __restrict__ eids,
    float* __restrict__ sumrel, float* __restrict__ cntf, float* __restrict__ outsrc) {
  int w = (blockIdx.x * 256 + threadIdx.x) >> 6;
  int lane = threadIdx.x & 63;
  if (w >= RTOT) return;
  int b = w / Nn;
  const size_t ebase = (size_t)b * En;
  const size_t nbase = (size_t)b * Nn;
  int s0 = offs[w], s1 = s0 + cnt[w];
  float r0=0,r1=0,r2=0,r3=0, a0=0,a1=0,a2=0,a3=0, cf=0;
  for (int base = s0; base < s1; base += 64) {
    int k = s1 - base; if (k > 64) k = 64;
    int e = 0, sr = 0; float m = 0.f;
    if (lane < k) {
      e  = eids[base + lane];
      sr = ei[(ebase + e)*2];
      m  = emask[ebase + e];
    }
    int e0 = __shfl(e, 0), sr0 = __shfl(sr, 0);
    float m0 = __shfl(m, 0);
    float4 rvA = *(const float4*)(erel  + (ebase + e0)*Dn + lane*4);
    float4 nvA = *(const float4*)(nodef + (nbase + sr0)*Dn + lane*4);
    for (int j = 0; j < k; j++) {
      float4 rvB = make_float4(0,0,0,0), nvB = make_float4(0,0,0,0);
      float m1 = 0.f;
      if (j + 1 < k) {
        int e1 = __shfl(e, j+1), sr1 = __shfl(sr, j+1);
        m1 = __shfl(m, j+1);
        rvB = *(const float4*)(erel  + (ebase + e1)*Dn + lane*4);
        nvB = *(const float4*)(nodef + (nbase + sr1)*Dn + lane*4);
      }
      r0 += rvA.x*m0; r1 += rvA.y*m0; r2 += rvA.z*m0; r3 += rvA.w*m0;
      a0 += nvA.x*m0; a1 += nvA.y*m0; a2 += nvA.z*m0; a3 += nvA.w*m0;
      cf += m0;
      rvA = rvB; nvA = nvB; m0 = m1;
    }
  }
  size_t ob = (size_t)w*Dn + lane*4;
  *(float4*)(sumrel + ob) = make_float4(r0,r1,r2,r3);
  *(float4*)(outsrc + ob) = make_float4(a0,a1,a2,a3);
  if (lane == 0) cntf[w] = cf;
}

// ---------- helpers ----------
template<int MR>
__device__ __forceinline__ void stageX(const float* __restrict__ src, char* lds, int row0, int tid) {
#pragma unroll
  for (int i = 0; i < MR*4; i++) {
    int flat = tid + 256*i;
    int r = flat >> 6, c4 = flat & 63;
    float4 v = *(const float4*)(src + (size_t)(row0 + r)*Dn + c4*4);
    short4 s; s.x=f2b(v.x); s.y=f2b(v.y); s.z=f2b(v.z); s.w=f2b(v.w);
    int byte = r*512 + ((c4*8) ^ ((r & 7) << 4));
    *(short4*)(lds + byte) = s;
  }
}

__device__ __forceinline__ bf16x8 ldsA(const char* lds, int r, int kb) {
  int byte = r*512 + (((kb)*2) ^ ((r & 7) << 4));
  return *(const bf16x8*)(lds + byte);
}

template<int MR>
__device__ __forceinline__ void ln_write(f32x4 (&acc)[MR][4], float* red,
    const float* __restrict__ sc, const float* __restrict__ bi,
    float* __restrict__ out, int row0, int lane, int wv) {
  constexpr int R = MR*16;
  int l15 = lane & 15, l4 = lane >> 4;
  int cols[4]; float sc_c[4], bi_c[4];
#pragma unroll
  for (int n = 0; n < 4; n++) {
    cols[n] = wv*64 + n*16 + l15;
    sc_c[n] = sc[cols[n]]; bi_c[n] = bi[cols[n]];
  }
  float s1[MR][4], s2[MR][4];
#pragma unroll
  for (int m = 0; m < MR; m++)
#pragma unroll
    for (int g = 0; g < 4; g++) {
      float a = 0.f, b = 0.f;
#pragma unroll
      for (int n = 0; n < 4; n++) { float p = acc[m][n][g]; a += p; b += p*p; }
#pragma unroll
      for (int d = 1; d < 16; d <<= 1) { a += __shfl_xor(a, d, 16); b += __shfl_xor(b, d, 16); }
      s1[m][g] = a; s2[m][g] = b;
    }
  if (l15 == 0) {
#pragma unroll
    for (int m = 0; m < MR; m++)
#pragma unroll
      for (int g = 0; g < 4; g++) {
        int r = m*16 + l4*4 + g;
        red[(wv*R + r)*2]     = s1[m][g];
        red[(wv*R + r)*2 + 1] = s2[m][g];
      }
  }
  __syncthreads();
#pragma unroll
  for (int m = 0; m < MR; m++)
#pragma unroll
    for (int g = 0; g < 4; g++) {
      int r = m*16 + l4*4 + g; int rg = row0 + r;
      float t1 = 0.f, t2 = 0.f;
#pragma unroll
      for (int u = 0; u < 4; u++) { t1 += red[(u*R + r)*2]; t2 += red[(u*R + r)*2 + 1]; }
      float mean = t1 * (1.0f/Dn);
      float var  = t2 * (1.0f/Dn) - mean*mean;
      float rstd = rsqrtf(var + 1e-5f);
#pragma unroll
      for (int n = 0; n < 4; n++)
        out[(size_t)rg*Dn + cols[n]] = (acc[m][n][g] - mean)*rstd*sc_c[n] + bi_c[n];
    }
}

// ---------- K3: relln ----------
__global__ void __launch_bounds__(256, 4) relln(
    const float* __restrict__ sumrel, const short* __restrict__ relwT,
    const float* __restrict__ relb, const float* __restrict__ nodef,
    const float* __restrict__ cntf, const float* __restrict__ ns,
    const float* __restrict__ nb, float* __restrict__ xout) {
  constexpr int MR = 2;
  __shared__ __align__(16) char lds[16384 + 1024];
  float* red = (float*)(lds + 16384);
  int tid = threadIdx.x;
  int lane = tid & 63, wv = tid >> 6;
  int l15 = lane & 15, l4 = lane >> 4;
  int row0 = blockIdx.x * (MR*16);
  stageX<MR>(sumrel, lds, row0, tid);
  __syncthreads();
  f32x4 acc[MR][4] = {};
#pragma unroll
  for (int ks = 0; ks < 8; ks++) {
    bf16x8 af[MR], bfr[4];
#pragma unroll
    for (int m = 0; m < MR; m++) af[m] = ldsA(lds, m*16 + l15, ks*32 + l4*8);
#pragma unroll
    for (int n = 0; n < 4; n++) {
      int col = wv*64 + n*16 + l15;
      bfr[n] = *(const bf16x8*)(relwT + col*Dn + ks*32 + l4*8);
    }
#pragma unroll
    for (int m = 0; m < MR; m++)
#pragma unroll
      for (int n = 0; n < 4; n++)
        acc[m][n] = __builtin_amdgcn_mfma_f32_16x16x32_bf16(af[m], bfr[n], acc[m][n], 0, 0, 0);
  }
  int cols[4]; float rb_c[4];
#pragma unroll
  for (int n = 0; n < 4; n++) { cols[n] = wv*64 + n*16 + l15; rb_c[n] = relb[cols[n]]; }
#pragma unroll
  for (int m = 0; m < MR; m++)
#pragma unroll
    for (int g = 0; g < 4; g++) {
      int r = m*16 + l4*4 + g; int rg = row0 + r;
      float cf  = cntf[rg];
      float inv = 1.0f / fmaxf(cf, 1.0f);
#pragma unroll
      for (int n = 0; n < 4; n++) {
        float ssrc = xout[(size_t)rg*Dn + cols[n]];
        float nfv  = nodef[(size_t)rg*Dn + cols[n]];
        float aggv = (ssrc + acc[m][n][g] + cf*rb_c[n]) * inv;
        acc[m][n][g] = nfv + aggv;
      }
    }
  ln_write<MR>(acc, red, ns, nb, xout, row0, lane, wv);
}

// ---------- K4: FFN v7 — 256 thr, FBM=32, X in LDS, weights direct from L2, 4 blocks/CU ----------
#define FBM 32

__global__ void __launch_bounds__(256, 4) ffnk(
    const short* __restrict__ w1T, const float* __restrict__ b1,
    const short* __restrict__ w2T, const float* __restrict__ b2,
    const float* __restrict__ fs, const float* __restrict__ fb,
    float* __restrict__ xio) {
  __shared__ __align__(16) char lds[16384 + 4096 + 1024];
  char* Xs = lds;                      // 32 rows x 512B (swizzled)
  char* Hs = lds + 16384;              // 32 rows x 128B (swizzled)
  float* red = (float*)(lds + 16384 + 4096);

  int tid = threadIdx.x;
  int lane = tid & 63, wn = tid >> 6;  // 4 waves, each owns 16 GEMM1-cols / 64 out-cols
  int l15 = lane & 15, l4 = lane >> 4;
  int row0 = blockIdx.x * FBM;
  int cl = wn*16 + l15;                // GEMM1 H-col (within 64-chunk)

  stageX<2>(xio, Xs, row0, tid);
  __syncthreads();

  f32x4 acc2[2][4] = {};

#pragma unroll 1
  for (int hc = 0; hc < 16; hc++) {
    // ---- GEMM1 (swapped): w1 fragments direct from L2, X from LDS ----
    f32x4 acc1[2] = {};
    const short* w1p = w1T + (size_t)(hc*64 + cl)*Dn + l4*8;
#pragma unroll
    for (int ks = 0; ks < 8; ks++) {
      bf16x8 w1f = *(const bf16x8*)(w1p + ks*32);
#pragma unroll
      for (int mf = 0; mf < 2; mf++) {
        bf16x8 xfr = ldsA(Xs, mf*16 + l15, ks*32 + l4*8);
        acc1[mf] = __builtin_amdgcn_mfma_f32_16x16x32_bf16(w1f, xfr, acc1[mf], 0, 0, 0);
      }
    }

    // ---- bias + gelu -> Hs (short4, swizzled, conflict-free) ----
    float4 b1v = *(const float4*)(b1 + hc*64 + wn*16 + l4*4);
#pragma unroll
    for (int mf = 0; mf < 2; mf++) {
      short4 s;
      s.x = f2b(gelu_f(acc1[mf][0] + b1v.x));
      s.y = f2b(gelu_f(acc1[mf][1] + b1v.y));
      s.z = f2b(gelu_f(acc1[mf][2] + b1v.z));
      s.w = f2b(gelu_f(acc1[mf][3] + b1v.w));
      int R = mf*16 + l15;
      *(short4*)(Hs + R*128 + ((wn*32 + l4*8) ^ ((R & 7) << 4))) = s;
    }
    __syncthreads();                    // Hs ready

    // ---- GEMM2: acc2 += H(32x64) @ W2chunk(64x256); W2 direct from L2 ----
#pragma unroll
    for (int ksl = 0; ksl < 2; ksl++) {
      bf16x8 ah[2];
#pragma unroll
      for (int mf = 0; mf < 2; mf++) {
        int rr = mf*16 + l15;
        ah[mf] = *(const bf16x8*)(Hs + rr*128 + (((ksl*32 + l4*8)*2) ^ ((rr & 7) << 4)));
      }
#pragma unroll
      for (int nf = 0; nf < 4; nf++) {
        int oc = wn*64 + nf*16 + l15;
        bf16x8 bw = *(const bf16x8*)(w2T + (size_t)oc*Hn + hc*64 + ksl*32 + l4*8);
#pragma unroll
        for (int mf = 0; mf < 2; mf++)
          acc2[mf][nf] = __builtin_amdgcn_mfma_f32_16x16x32_bf16(ah[mf], bw, acc2[mf][nf], 0, 0, 0);
      }
    }
    __syncthreads();                    // Hs free for next hc
  }

  // ---- epilogue: residual + b2, LayerNorm over 256 cols (4 wn-waves share rows) ----
  float b2c[4], fsc[4], fbc[4];
#pragma unroll
  for (int nf = 0; nf < 4; nf++) {
    int col = wn*64 + nf*16 + l15;
    b2c[nf] = b2[col]; fsc[nf] = fs[col]; fbc[nf] = fb[col];
  }
#pragma unroll
  for (int mf = 0; mf < 2; mf++)
#pragma unroll
    for (int g = 0; g < 4; g++) {
      int R = mf*16 + l4*4 + g;
      int rg = row0 + R;
      float a = 0.f, q = 0.f;
#pragma unroll
      for (int nf = 0; nf < 4; nf++) {
        int col = wn*64 + nf*16 + l15;
        float xv = xio[(size_t)rg*Dn + col];
        float vv = xv + acc2[mf][nf][g] + b2c[nf];
        acc2[mf][nf][g] = vv;
        a += vv; q += vv*vv;
      }
#pragma unroll
      for (int d = 1; d < 16; d <<= 1) { a += __shfl_xor(a, d, 16); q += __shfl_xor(q, d, 16); }
      if (l15 == 0) {
        red[(wn*FBM + R)*2]     = a;
        red[(wn*FBM + R)*2 + 1] = q;
      }
    }
  __syncthreads();
#pragma unroll
  for (int mf = 0; mf < 2; mf++)
#pragma unroll
    for (int g = 0; g < 4; g++) {
      int R = mf*16 + l4*4 + g;
      int rg = row0 + R;
      float t1 = 0.f, t2 = 0.f;
#pragma unroll
      for (int u = 0; u < 4; u++) { t1 += red[(u*FBM + R)*2]; t2 += red[(u*FBM + R)*2 + 1]; }
      float mean = t1 * (1.0f/Dn);
      float var  = t2 * (1.0f/Dn) - mean*mean;
      float rstd = rsqrtf(var + 1e-5f);
#pragma unroll
      for (int nf = 0; nf < 4; nf++) {
        int col = wn*64 + nf*16 + l15;
        xio[(size_t)rg*Dn + col] = (acc2[mf][nf][g] - mean)*rstd*fsc[nf] + fbc[nf];
      }
    }
}

// ---------- host ----------
extern "C" void kernel_launch(void* const* d_in, const int* in_sizes, int n_in,
                              void* d_out, int out_size, void* d_ws, size_t ws_size,
                              hipStream_t stream) {
  const float* nodef = (const float*)d_in[0];
  const float* erel  = (const float*)d_in[1];
  const float* emask = (const float*)d_in[2];
  const float* relw  = (const float*)d_in[3];
  const float* relb  = (const float*)d_in[4];
  const float* ns    = (const float*)d_in[5];
  const float* nb    = (const float*)d_in[6];
  const float* w1    = (const float*)d_in[7];
  const float* b1    = (const float*)d_in[8];
  const float* w2    = (const float*)d_in[9];
  const float* b2    = (const float*)d_in[10];
  const float* fs    = (const float*)d_in[11];
  const float* fb    = (const float*)d_in[12];
  const int*   ei    = (const int*)d_in[13];
  float* out = (float*)d_out;
  char* ws = (char*)d_ws;

  constexpr size_t SZ_SUMREL = (size_t)RTOT * Dn * 4;
  constexpr size_t O_CNT  = SZ_SUMREL;
  constexpr size_t O_CUR  = O_CNT + (size_t)RTOT*4;
  constexpr size_t O_OFF  = O_CUR + (size_t)RTOT*4;
  constexpr size_t O_EID  = O_OFF + ((size_t)(RTOT+1)*4 + 124);
  constexpr size_t O_CNTF = O_EID + (size_t)Bn*En*4;
  constexpr size_t O_RWT  = O_CNTF + (size_t)RTOT*4;
  constexpr size_t O_W1T  = O_RWT + (size_t)Dn*Dn*2;
  constexpr size_t O_W2T  = O_W1T + (size_t)Dn*Hn*2;
  constexpr size_t WS_NEED = O_W2T + (size_t)Hn*Dn*2;
  if (ws_size < WS_NEED) return;

  float* sumrel = (float*)(ws);
  int*   cnt    = (int*)(ws + O_CNT);
  int*   cursor = (int*)(ws + O_CUR);
  int*   offs   = (int*)(ws + O_OFF);
  int*   eids   = (int*)(ws + O_EID);
  float* cntf   = (float*)(ws + O_CNTF);
  short* relwT  = (short*)(ws + O_RWT);
  short* w1T    = (short*)(ws + O_W1T);
  short* w2T    = (short*)(ws + O_W2T);
  int*   gtot   = offs + RTOT;          // zeroed by the memset below

  hipMemsetAsync(ws + O_CNT, 0, O_EID - O_CNT, stream);

  wconv<<<(Dn*Dn + Dn*Hn + Hn*Dn) / 256, 256, 0, stream>>>(relw, w1, w2, relwT, w1T, w2T);
  histk<<<(Bn*En) / 256, 256, 0, stream>>>(ei, cnt);
  offsk<<<(RTOT + 255) / 256, 256, 0, stream>>>(cnt, offs, gtot);
  fillk<<<(Bn*En) / 256, 256, 0, stream>>>(ei, offs, cursor, eids);
  aggk<<<(RTOT + 3) / 4, 256, 0, stream>>>(nodef, erel, emask, ei, offs, cnt, eids, sumrel, cntf, out);
  relln<<<RTOT / 32, 256, 0, stream>>>(sumrel, relwT, relb, nodef, cntf, ns, nb, out);
  ffnk<<<RTOT / FBM, 256, 0, stream>>>(w1T, b1, w2T, b2, fs, fb, out);
}

// Round 7
// 673.484 us; speedup vs baseline: 1.9242x; 1.2098x over previous
//
#include <hip/hip_runtime.h>
#include <math.h>

#define Bn 2
#define Nn 50000
#define En 262144
#define Dn 256
#define Hn 1024
#define RTOT (Bn*Nn)
#define RHALF 50000

typedef short bf16x8 __attribute__((ext_vector_type(8)));
typedef float f32x4 __attribute__((ext_vector_type(4)));

__device__ __forceinline__ short f2b(float f) {
  unsigned u = __float_as_uint(f);
  u = u + 0x7fffu + ((u >> 16) & 1u);   // RNE to bf16
  return (short)(u >> 16);
}

// 3-term A&S 7.1.25 erf, |err|<=2.5e-5 (plenty for bf16 output)
__device__ __forceinline__ float gelu_f(float v) {
  float x = fabsf(v) * 0.70710678118654752f;
  float t = __builtin_amdgcn_rcpf(1.0f + 0.47047f * x);
  float p = t*(0.3480242f + t*(-0.0958798f + t*0.7478556f));
  float er = 1.0f - p * __expf(-x*x);
  er = copysignf(er, v);
  return 0.5f * v * (1.0f + er);
}

__device__ __forceinline__ void gl16(const void* g, void* l) {
  __builtin_amdgcn_global_load_lds(
      (const __attribute__((address_space(1))) unsigned int*)g,
      (__attribute__((address_space(3))) unsigned int*)l, 16, 0, 0);
}

// ---------- weight prep: relwT plain; w1s/w2s pre-swizzled for gload_lds ----------
// w1s: [kk<4][col<1024][kl<64]  idx = kk*65536 + col*64 + (kl ^ ((col&7)<<3))
// w2s: [kk<16][col<256][kl<64]  idx = kk*16384 + col*64 + (kl ^ ((col&7)<<3))
__global__ void __launch_bounds__(256) wconv(
    const float* __restrict__ relw, const float* __restrict__ w1,
    const float* __restrict__ w2, short* __restrict__ relwT,
    short* __restrict__ w1s, short* __restrict__ w2s) {
  int tid = blockIdx.x * 256 + threadIdx.x;
  if (tid < Dn*Dn) { int c = tid >> 8, k = tid & 255; relwT[tid] = f2b(relw[k*Dn + c]); }
  int t1 = tid - Dn*Dn;
  if (t1 >= 0 && t1 < Dn*Hn) {
    int kk = t1 >> 16, rem = t1 & 65535;
    int col = rem >> 6, kl = rem & 63;
    w1s[kk*65536 + col*64 + (kl ^ ((col & 7) << 3))] = f2b(w1[(kk*64 + kl)*Hn + col]);
  }
  int t2 = tid - Dn*Dn - Dn*Hn;
  if (t2 >= 0 && t2 < Hn*Dn) {
    int kk = t2 >> 14, rem = t2 & 16383;
    int col = rem >> 6, kl = rem & 63;
    w2s[kk*16384 + col*64 + (kl ^ ((col & 7) << 3))] = f2b(w2[(kk*64 + kl)*Dn + col]);
  }
}

// ---------- CSR build ----------
__global__ void __launch_bounds__(256) histk(const int* __restrict__ ei, int* __restrict__ cnt) {
  int tid = blockIdx.x * 256 + threadIdx.x;
  if (tid >= Bn*En) return;
  int b = tid / En;
  int tgt = ei[tid*2 + 1];
  atomicAdd(&cnt[b*Nn + tgt], 1);
}

__global__ void __launch_bounds__(256) offsk(const int* __restrict__ cnt,
                                             int* __restrict__ offs, int* __restrict__ gtot) {
  int i = blockIdx.x * 256 + threadIdx.x;
  int lane = threadIdx.x & 63;
  int v = (i < RTOT) ? cnt[i] : 0;
  int s = v;
#pragma unroll
  for (int d = 1; d < 64; d <<= 1) {
    int t = __shfl_up(s, d, 64);
    if (lane >= d) s += t;
  }
  int base = 0;
  if (lane == 63) base = atomicAdd(gtot, s);
  base = __shfl(base, 63, 64);
  if (i < RTOT) offs[i] = base + s - v;
}

__global__ void __launch_bounds__(256) fillk(const int* __restrict__ ei, const int* __restrict__ offs,
                                             int* __restrict__ cursor, int* __restrict__ eids) {
  int tid = blockIdx.x * 256 + threadIdx.x;
  if (tid >= Bn*En) return;
  int b = tid / En, e = tid - b*En;
  int tgt = ei[tid*2 + 1];
  int node = b*Nn + tgt;
  int pos = atomicAdd(&cursor[node], 1);
  eids[offs[node] + pos] = e;
}

// ---------- aggregation ----------
__global__ void __launch_bounds__(256) aggk(
    const float* __restrict__ nodef, const float* __restrict__ erel,
    const float* __restrict__ emask, const int* __restrict__ ei,
    const int* __restrict__ offs, const int* __restrict__ cnt,
    const int* __restrict__ eids,
    float* __restrict__ sumrel, float* __restrict__ cntf, float* __restrict__ outsrc) {
  int w = (blockIdx.x * 256 + threadIdx.x) >> 6;
  int lane = threadIdx.x & 63;
  if (w >= RTOT) return;
  int b = w / Nn;
  const size_t ebase = (size_t)b * En;
  const size_t nbase = (size_t)b * Nn;
  int s0 = offs[w], s1 = s0 + cnt[w];
  float r0=0,r1=0,r2=0,r3=0, a0=0,a1=0,a2=0,a3=0, cf=0;
  for (int base = s0; base < s1; base += 64) {
    int k = s1 - base; if (k > 64) k = 64;
    int e = 0, sr = 0; float m = 0.f;
    if (lane < k) {
      e  = eids[base + lane];
      sr = ei[(ebase + e)*2];
      m  = emask[ebase + e];
    }
    int e0 = __shfl(e, 0), sr0 = __shfl(sr, 0);
    float m0 = __shfl(m, 0);
    float4 rvA = *(const float4*)(erel  + (ebase + e0)*Dn + lane*4);
    float4 nvA = *(const float4*)(nodef + (nbase + sr0)*Dn + lane*4);
    for (int j = 0; j < k; j++) {
      float4 rvB = make_float4(0,0,0,0), nvB = make_float4(0,0,0,0);
      float m1 = 0.f;
      if (j + 1 < k) {
        int e1 = __shfl(e, j+1), sr1 = __shfl(sr, j+1);
        m1 = __shfl(m, j+1);
        rvB = *(const float4*)(erel  + (ebase + e1)*Dn + lane*4);
        nvB = *(const float4*)(nodef + (nbase + sr1)*Dn + lane*4);
      }
      r0 += rvA.x*m0; r1 += rvA.y*m0; r2 += rvA.z*m0; r3 += rvA.w*m0;
      a0 += nvA.x*m0; a1 += nvA.y*m0; a2 += nvA.z*m0; a3 += nvA.w*m0;
      cf += m0;
      rvA = rvB; nvA = nvB; m0 = m1;
    }
  }
  size_t ob = (size_t)w*Dn + lane*4;
  *(float4*)(sumrel + ob) = make_float4(r0,r1,r2,r3);
  *(float4*)(outsrc + ob) = make_float4(a0,a1,a2,a3);
  if (lane == 0) cntf[w] = cf;
}

// ---------- helpers for relln ----------
template<int MR>
__device__ __forceinline__ void stageX(const float* __restrict__ src, char* lds, int row0, int tid) {
#pragma unroll
  for (int i = 0; i < MR*4; i++) {
    int flat = tid + 256*i;
    int r = flat >> 6, c4 = flat & 63;
    float4 v = *(const float4*)(src + (size_t)(row0 + r)*Dn + c4*4);
    short4 s; s.x=f2b(v.x); s.y=f2b(v.y); s.z=f2b(v.z); s.w=f2b(v.w);
    int byte = r*512 + ((c4*8) ^ ((r & 7) << 4));
    *(short4*)(lds + byte) = s;
  }
}

__device__ __forceinline__ bf16x8 ldsA(const char* lds, int r, int kb) {
  int byte = r*512 + (((kb)*2) ^ ((r & 7) << 4));
  return *(const bf16x8*)(lds + byte);
}

template<int MR>
__device__ __forceinline__ void ln_write(f32x4 (&acc)[MR][4], float* red,
    const float* __restrict__ sc, const float* __restrict__ bi,
    float* __restrict__ out, int row0, int lane, int wv) {
  constexpr int R = MR*16;
  int l15 = lane & 15, l4 = lane >> 4;
  int cols[4]; float sc_c[4], bi_c[4];
#pragma unroll
  for (int n = 0; n < 4; n++) {
    cols[n] = wv*64 + n*16 + l15;
    sc_c[n] = sc[cols[n]]; bi_c[n] = bi[cols[n]];
  }
  float s1[MR][4], s2[MR][4];
#pragma unroll
  for (int m = 0; m < MR; m++)
#pragma unroll
    for (int g = 0; g < 4; g++) {
      float a = 0.f, b = 0.f;
#pragma unroll
      for (int n = 0; n < 4; n++) { float p = acc[m][n][g]; a += p; b += p*p; }
#pragma unroll
      for (int d = 1; d < 16; d <<= 1) { a += __shfl_xor(a, d, 16); b += __shfl_xor(b, d, 16); }
      s1[m][g] = a; s2[m][g] = b;
    }
  if (l15 == 0) {
#pragma unroll
    for (int m = 0; m < MR; m++)
#pragma unroll
      for (int g = 0; g < 4; g++) {
        int r = m*16 + l4*4 + g;
        red[(wv*R + r)*2]     = s1[m][g];
        red[(wv*R + r)*2 + 1] = s2[m][g];
      }
  }
  __syncthreads();
#pragma unroll
  for (int m = 0; m < MR; m++)
#pragma unroll
    for (int g = 0; g < 4; g++) {
      int r = m*16 + l4*4 + g; int rg = row0 + r;
      float t1 = 0.f, t2 = 0.f;
#pragma unroll
      for (int u = 0; u < 4; u++) { t1 += red[(u*R + r)*2]; t2 += red[(u*R + r)*2 + 1]; }
      float mean = t1 * (1.0f/Dn);
      float var  = t2 * (1.0f/Dn) - mean*mean;
      float rstd = rsqrtf(var + 1e-5f);
#pragma unroll
      for (int n = 0; n < 4; n++)
        out[(size_t)rg*Dn + cols[n]] = (acc[m][n][g] - mean)*rstd*sc_c[n] + bi_c[n];
    }
}

// ---------- K3: relln ----------
__global__ void __launch_bounds__(256, 4) relln(
    const float* __restrict__ sumrel, const short* __restrict__ relwT,
    const float* __restrict__ relb, const float* __restrict__ nodef,
    const float* __restrict__ cntf, const float* __restrict__ ns,
    const float* __restrict__ nb, float* __restrict__ xout) {
  constexpr int MR = 2;
  __shared__ __align__(16) char lds[16384 + 1024];
  float* red = (float*)(lds + 16384);
  int tid = threadIdx.x;
  int lane = tid & 63, wv = tid >> 6;
  int l15 = lane & 15, l4 = lane >> 4;
  int row0 = blockIdx.x * (MR*16);
  stageX<MR>(sumrel, lds, row0, tid);
  __syncthreads();
  f32x4 acc[MR][4] = {};
#pragma unroll
  for (int ks = 0; ks < 8; ks++) {
    bf16x8 af[MR], bfr[4];
#pragma unroll
    for (int m = 0; m < MR; m++) af[m] = ldsA(lds, m*16 + l15, ks*32 + l4*8);
#pragma unroll
    for (int n = 0; n < 4; n++) {
      int col = wv*64 + n*16 + l15;
      bfr[n] = *(const bf16x8*)(relwT + col*Dn + ks*32 + l4*8);
    }
#pragma unroll
    for (int m = 0; m < MR; m++)
#pragma unroll
      for (int n = 0; n < 4; n++)
        acc[m][n] = __builtin_amdgcn_mfma_f32_16x16x32_bf16(af[m], bfr[n], acc[m][n], 0, 0, 0);
  }
  int cols[4]; float rb_c[4];
#pragma unroll
  for (int n = 0; n < 4; n++) { cols[n] = wv*64 + n*16 + l15; rb_c[n] = relb[cols[n]]; }
#pragma unroll
  for (int m = 0; m < MR; m++)
#pragma unroll
    for (int g = 0; g < 4; g++) {
      int r = m*16 + l4*4 + g; int rg = row0 + r;
      float cf  = cntf[rg];
      float inv = 1.0f / fmaxf(cf, 1.0f);
#pragma unroll
      for (int n = 0; n < 4; n++) {
        float ssrc = xout[(size_t)rg*Dn + cols[n]];
        float nfv  = nodef[(size_t)rg*Dn + cols[n]];
        float aggv = (ssrc + acc[m][n][g] + cf*rb_c[n]) * inv;
        acc[m][n][g] = nfv + aggv;
      }
    }
  ln_write<MR>(acc, red, ns, nb, xout, row0, lane, wv);
}

// ---------- FFN GEMM1: H[r][c] = gelu(x @ w1 + b1), half at a time ----------
// grid (391, 8); tile 128M x 128N, K=256 (4 steps of 64). H stored pre-swizzled:
// Hbyte = r*2048 + (c>>6)*128 + (((c&63)*2) ^ ((r&7)<<4))
__global__ void __launch_bounds__(512, 4) ffn1k(
    const float* __restrict__ x, const short* __restrict__ w1s,
    const float* __restrict__ b1, short* __restrict__ H, int gstart) {
  __shared__ __align__(16) char lds[32768];
  char* Xa = lds;            // 128 rows x 128B (swizzled)
  char* W1a = lds + 16384;   // 128 cols x 128B (swizzled)
  int tid = threadIdx.x;
  int lane = tid & 63, wv = tid >> 6;
  int l15 = lane & 15, l4 = lane >> 4;
  int wm = wv >> 2, wn = wv & 3;       // 2m x 4n
  int row0 = blockIdx.x * 128;
  int col0 = blockIdx.y * 128;

  f32x4 acc[4][2] = {};
#pragma unroll 1
  for (int kk = 0; kk < 4; kk++) {
    // stage X (reg-staged f32->bf16, swizzled)
    {
      int r = tid >> 2, kb = (tid & 3) * 16;
      int gr = gstart + row0 + r;
      if (gr > RTOT - 1) gr = RTOT - 1;
      const float* p = x + (size_t)gr*Dn + kk*64 + kb;
      float4 v0 = *(const float4*)(p);
      float4 v1 = *(const float4*)(p + 4);
      float4 v2 = *(const float4*)(p + 8);
      float4 v3 = *(const float4*)(p + 12);
      bf16x8 s0, s1;
      s0[0]=f2b(v0.x); s0[1]=f2b(v0.y); s0[2]=f2b(v0.z); s0[3]=f2b(v0.w);
      s0[4]=f2b(v1.x); s0[5]=f2b(v1.y); s0[6]=f2b(v1.z); s0[7]=f2b(v1.w);
      s1[0]=f2b(v2.x); s1[1]=f2b(v2.y); s1[2]=f2b(v2.z); s1[3]=f2b(v2.w);
      s1[4]=f2b(v3.x); s1[5]=f2b(v3.y); s1[6]=f2b(v3.z); s1[7]=f2b(v3.w);
      *(bf16x8*)(Xa + r*128 + ((kb*2)      ^ ((r & 7) << 4))) = s0;
      *(bf16x8*)(Xa + r*128 + ((kb*2 + 16) ^ ((r & 7) << 4))) = s1;
    }
    // stage W1 chunk via gload_lds (pre-swizzled source, linear dest)
#pragma unroll
    for (int i = 0; i < 2; i++) {
      int base = wv*2048 + i*1024;
      gl16((const char*)w1s + (size_t)kk*131072 + col0*128 + base + lane*16,
           W1a + base + lane*16);
    }
    __syncthreads();
    // compute
#pragma unroll
    for (int ksl = 0; ksl < 2; ksl++) {
      bf16x8 af[4], bw[2];
#pragma unroll
      for (int mf = 0; mf < 4; mf++) {
        int r = wm*64 + mf*16 + l15;
        af[mf] = *(const bf16x8*)(Xa + r*128 + (((ksl*32 + l4*8)*2) ^ ((r & 7) << 4)));
      }
#pragma unroll
      for (int nf = 0; nf < 2; nf++) {
        int c = wn*32 + nf*16 + l15;
        bw[nf] = *(const bf16x8*)(W1a + c*128 + (((ksl*32 + l4*8)*2) ^ ((c & 7) << 4)));
      }
#pragma unroll
      for (int mf = 0; mf < 4; mf++)
#pragma unroll
        for (int nf = 0; nf < 2; nf++)
          acc[mf][nf] = __builtin_amdgcn_mfma_f32_16x16x32_bf16(af[mf], bw[nf], acc[mf][nf], 0, 0, 0);
    }
    __syncthreads();
  }
  // epilogue: bias+gelu -> LDS [128r][128c] (swizzled 256B rows) -> 16B H stores
  float b1v[2];
#pragma unroll
  for (int nf = 0; nf < 2; nf++) b1v[nf] = b1[col0 + wn*32 + nf*16 + l15];
#pragma unroll
  for (int mf = 0; mf < 4; mf++)
#pragma unroll
    for (int g = 0; g < 4; g++) {
      int R = wm*64 + mf*16 + l4*4 + g;
#pragma unroll
      for (int nf = 0; nf < 2; nf++) {
        int C = wn*32 + nf*16 + l15;
        float hv = gelu_f(acc[mf][nf][g] + b1v[nf]);
        *(short*)(lds + R*256 + ((C*2) ^ ((R & 7) << 4))) = f2b(hv);
      }
    }
  __syncthreads();
#pragma unroll
  for (int i = 0; i < 4; i++) {
    int flat = tid + i*512;
    int r = flat >> 4, c8 = (flat & 15) * 8;
    if (row0 + r >= RHALF) continue;
    bf16x8 v = *(const bf16x8*)(lds + r*256 + ((c8*2) ^ ((r & 7) << 4)));
    int gc = col0 + c8;
    size_t hb = (size_t)(row0 + r)*2048 + (gc >> 6)*128 + (((gc & 63)*2) ^ (((row0 + r) & 7) << 4));
    *(bf16x8*)((char*)H + hb) = v;
  }
}

// ---------- FFN GEMM2: out = LN(x + H @ w2 + b2), half at a time ----------
// grid 782; tile 64M x 256N, K=1024 (16 steps of 64)
__global__ void __launch_bounds__(512, 4) ffn2k(
    const short* __restrict__ H, const short* __restrict__ w2s,
    const float* __restrict__ b2, const float* __restrict__ fs,
    const float* __restrict__ fb, float* __restrict__ xio, int gstart) {
  __shared__ __align__(16) char lds[8192 + 32768];
  char* Ha  = lds;            // 64 rows x 128B (swizzled)
  char* W2a = lds + 8192;     // 256 cols x 128B (swizzled)
  float* red = (float*)lds;   // aliases Ha after the loop
  int tid = threadIdx.x;
  int lane = tid & 63, wv = tid >> 6;
  int l15 = lane & 15, l4 = lane >> 4;
  int wm = wv >> 2, wn = wv & 3;       // 2m x 4n
  int rows0 = blockIdx.x * 64;

  f32x4 acc[2][4] = {};
#pragma unroll 1
  for (int kk = 0; kk < 16; kk++) {
    // stage H tile: per-lane global addr (row-clamped), linear dest
    {
      int flat = wv*1024 + lane*16;
      int r = flat >> 7, bo = flat & 127;
      int lr = rows0 + r; if (lr > RHALF - 1) lr = RHALF - 1;
      gl16((const char*)H + (size_t)lr*2048 + kk*128 + bo, Ha + flat);
    }
    // stage W2 chunk (32KB linear from pre-swizzled)
#pragma unroll
    for (int i = 0; i < 4; i++) {
      int base = wv*4096 + i*1024;
      gl16((const char*)w2s + (size_t)kk*32768 + base + lane*16, W2a + base + lane*16);
    }
    __syncthreads();
#pragma unroll
    for (int ksl = 0; ksl < 2; ksl++) {
      bf16x8 ah[2], bw[4];
#pragma unroll
      for (int mf = 0; mf < 2; mf++) {
        int r = wm*32 + mf*16 + l15;
        ah[mf] = *(const bf16x8*)(Ha + r*128 + (((ksl*32 + l4*8)*2) ^ ((r & 7) << 4)));
      }
#pragma unroll
      for (int nf = 0; nf < 4; nf++) {
        int c = wn*64 + nf*16 + l15;
        bw[nf] = *(const bf16x8*)(W2a + c*128 + (((ksl*32 + l4*8)*2) ^ ((c & 7) << 4)));
      }
#pragma unroll
      for (int mf = 0; mf < 2; mf++)
#pragma unroll
        for (int nf = 0; nf < 4; nf++)
          acc[mf][nf] = __builtin_amdgcn_mfma_f32_16x16x32_bf16(ah[mf], bw[nf], acc[mf][nf], 0, 0, 0);
    }
    __syncthreads();
  }
  // epilogue: + b2 + residual x, LayerNorm over 256 cols (4 wn-waves share rows)
  float b2c[4], fsc[4], fbc[4];
#pragma unroll
  for (int nf = 0; nf < 4; nf++) {
    int col = wn*64 + nf*16 + l15;
    b2c[nf] = b2[col]; fsc[nf] = fs[col]; fbc[nf] = fb[col];
  }
#pragma unroll
  for (int mf = 0; mf < 2; mf++)
#pragma unroll
    for (int g = 0; g < 4; g++) {
      int R = wm*32 + mf*16 + l4*4 + g;
      int lr = rows0 + R;
      bool ok = lr < RHALF;
      int gr = gstart + lr;
      float a = 0.f, q = 0.f;
#pragma unroll
      for (int nf = 0; nf < 4; nf++) {
        int col = wn*64 + nf*16 + l15;
        float xv = ok ? xio[(size_t)gr*Dn + col] : 0.f;
        float vv = xv + acc[mf][nf][g] + b2c[nf];
        acc[mf][nf][g] = vv;
        a += vv; q += vv*vv;
      }
#pragma unroll
      for (int d = 1; d < 16; d <<= 1) { a += __shfl_xor(a, d, 16); q += __shfl_xor(q, d, 16); }
      if (l15 == 0) {
        red[(wn*64 + R)*2]     = a;
        red[(wn*64 + R)*2 + 1] = q;
      }
    }
  __syncthreads();
#pragma unroll
  for (int mf = 0; mf < 2; mf++)
#pragma unroll
    for (int g = 0; g < 4; g++) {
      int R = wm*32 + mf*16 + l4*4 + g;
      int lr = rows0 + R;
      if (lr >= RHALF) continue;
      int gr = gstart + lr;
      float t1 = 0.f, t2 = 0.f;
#pragma unroll
      for (int u = 0; u < 4; u++) { t1 += red[(u*64 + R)*2]; t2 += red[(u*64 + R)*2 + 1]; }
      float mean = t1 * (1.0f/Dn);
      float var  = t2 * (1.0f/Dn) - mean*mean;
      float rstd = rsqrtf(var + 1e-5f);
#pragma unroll
      for (int nf = 0; nf < 4; nf++) {
        int col = wn*64 + nf*16 + l15;
        xio[(size_t)gr*Dn + col] = (acc[mf][nf][g] - mean)*rstd*fsc[nf] + fbc[nf];
      }
    }
}

// ---------- host ----------
extern "C" void kernel_launch(void* const* d_in, const int* in_sizes, int n_in,
                              void* d_out, int out_size, void* d_ws, size_t ws_size,
                              hipStream_t stream) {
  const float* nodef = (const float*)d_in[0];
  const float* erel  = (const float*)d_in[1];
  const float* emask = (const float*)d_in[2];
  const float* relw  = (const float*)d_in[3];
  const float* relb  = (const float*)d_in[4];
  const float* ns    = (const float*)d_in[5];
  const float* nb    = (const float*)d_in[6];
  const float* w1    = (const float*)d_in[7];
  const float* b1    = (const float*)d_in[8];
  const float* w2    = (const float*)d_in[9];
  const float* b2    = (const float*)d_in[10];
  const float* fs    = (const float*)d_in[11];
  const float* fb    = (const float*)d_in[12];
  const int*   ei    = (const int*)d_in[13];
  float* out = (float*)d_out;
  char* ws = (char*)d_ws;

  constexpr size_t SZ_SUMREL = (size_t)RTOT * Dn * 4;   // 102,400,000 == RHALF*Hn*2 (H half)
  constexpr size_t O_CNT  = SZ_SUMREL;
  constexpr size_t O_CUR  = O_CNT + (size_t)RTOT*4;
  constexpr size_t O_OFF  = O_CUR + (size_t)RTOT*4;
  constexpr size_t O_EID  = O_OFF + ((size_t)(RTOT+1)*4 + 124);
  constexpr size_t O_CNTF = O_EID + (size_t)Bn*En*4;
  constexpr size_t O_RWT  = O_CNTF + (size_t)RTOT*4;
  constexpr size_t O_W1T  = O_RWT + (size_t)Dn*Dn*2;
  constexpr size_t O_W2T  = O_W1T + (size_t)Dn*Hn*2;
  constexpr size_t WS_NEED = O_W2T + (size_t)Hn*Dn*2;
  if (ws_size < WS_NEED) return;

  float* sumrel = (float*)(ws);
  short* Hbuf   = (short*)(ws);          // overlays sumrel (dead after relln)
  int*   cnt    = (int*)(ws + O_CNT);
  int*   cursor = (int*)(ws + O_CUR);
  int*   offs   = (int*)(ws + O_OFF);
  int*   eids   = (int*)(ws + O_EID);
  float* cntf   = (float*)(ws + O_CNTF);
  short* relwT  = (short*)(ws + O_RWT);
  short* w1s    = (short*)(ws + O_W1T);
  short* w2s    = (short*)(ws + O_W2T);
  int*   gtot   = offs + RTOT;

  hipMemsetAsync(ws + O_CNT, 0, O_EID - O_CNT, stream);

  wconv<<<(Dn*Dn + Dn*Hn + Hn*Dn + 255) / 256, 256, 0, stream>>>(relw, w1, w2, relwT, w1s, w2s);
  histk<<<(Bn*En) / 256, 256, 0, stream>>>(ei, cnt);
  offsk<<<(RTOT + 255) / 256, 256, 0, stream>>>(cnt, offs, gtot);
  fillk<<<(Bn*En) / 256, 256, 0, stream>>>(ei, offs, cursor, eids);
  aggk<<<(RTOT + 3) / 4, 256, 0, stream>>>(nodef, erel, emask, ei, offs, cnt, eids, sumrel, cntf, out);
  relln<<<RTOT / 32, 256, 0, stream>>>(sumrel, relwT, relb, nodef, cntf, ns, nb, out);

  dim3 g1((RHALF + 127) / 128, Hn / 128);
  int g2 = (RHALF + 63) / 64;
  for (int half = 0; half < 2; half++) {
    int gstart = half * RHALF;
    ffn1k<<<g1, 512, 0, stream>>>(out, w1s, b1, Hbuf, gstart);
    ffn2k<<<g2, 512, 0, stream>>>(Hbuf, w2s, b2, fs, fb, out, gstart);
  }
}

// Round 8
// 633.175 us; speedup vs baseline: 2.0467x; 1.0637x over previous
//
#include <hip/hip_runtime.h>
#include <math.h>

#define Bn 2
#define Nn 50000
#define En 262144
#define Dn 256
#define Hn 1024
#define RTOT (Bn*Nn)

typedef short bf16x8 __attribute__((ext_vector_type(8)));
typedef float f32x4 __attribute__((ext_vector_type(4)));

__device__ __forceinline__ short f2b(float f) {
  unsigned u = __float_as_uint(f);
  u = u + 0x7fffu + ((u >> 16) & 1u);   // RNE to bf16
  return (short)(u >> 16);
}
__device__ __forceinline__ float b2f(unsigned short s) {
  return __uint_as_float(((unsigned)s) << 16);
}

// 3-term A&S 7.1.25 erf, |err|<=2.5e-5 (plenty for bf16 output)
__device__ __forceinline__ float gelu_f(float v) {
  float x = fabsf(v) * 0.70710678118654752f;
  float t = __builtin_amdgcn_rcpf(1.0f + 0.47047f * x);
  float p = t*(0.3480242f + t*(-0.0958798f + t*0.7478556f));
  float er = 1.0f - p * __expf(-x*x);
  er = copysignf(er, v);
  return 0.5f * v * (1.0f + er);
}

__device__ __forceinline__ void gl16(const void* g, void* l) {
  __builtin_amdgcn_global_load_lds(
      (const __attribute__((address_space(1))) unsigned int*)g,
      (__attribute__((address_space(3))) unsigned int*)l, 16, 0, 0);
}

// ---------- weight prep: relwT plain; w1s/w2s pre-swizzled for gload_lds ----------
// w1s: [kk<4][col<1024][kl<64]  short idx = kk*65536 + col*64 + (kl ^ ((col&7)<<3))
// w2s: [kk<16][col<256][kl<64]  short idx = kk*16384 + col*64 + (kl ^ ((col&7)<<3))
__global__ void __launch_bounds__(256) wconv(
    const float* __restrict__ relw, const float* __restrict__ w1,
    const float* __restrict__ w2, short* __restrict__ relwT,
    short* __restrict__ w1s, short* __restrict__ w2s) {
  int tid = blockIdx.x * 256 + threadIdx.x;
  if (tid < Dn*Dn) { int c = tid >> 8, k = tid & 255; relwT[tid] = f2b(relw[k*Dn + c]); }
  int t1 = tid - Dn*Dn;
  if (t1 >= 0 && t1 < Dn*Hn) {
    int kk = t1 >> 16, rem = t1 & 65535;
    int col = rem >> 6, kl = rem & 63;
    w1s[kk*65536 + col*64 + (kl ^ ((col & 7) << 3))] = f2b(w1[(kk*64 + kl)*Hn + col]);
  }
  int t2 = tid - Dn*Dn - Dn*Hn;
  if (t2 >= 0 && t2 < Hn*Dn) {
    int kk = t2 >> 14, rem = t2 & 16383;
    int col = rem >> 6, kl = rem & 63;
    w2s[kk*16384 + col*64 + (kl ^ ((col & 7) << 3))] = f2b(w2[(kk*64 + kl)*Dn + col]);
  }
}

// ---------- CSR build ----------
__global__ void __launch_bounds__(256) histk(const int* __restrict__ ei, int* __restrict__ cnt) {
  int tid = blockIdx.x * 256 + threadIdx.x;
  if (tid >= Bn*En) return;
  int b = tid / En;
  int tgt = ei[tid*2 + 1];
  atomicAdd(&cnt[b*Nn + tgt], 1);
}

__global__ void __launch_bounds__(256) offsk(const int* __restrict__ cnt,
                                             int* __restrict__ offs, int* __restrict__ gtot) {
  int i = blockIdx.x * 256 + threadIdx.x;
  int lane = threadIdx.x & 63;
  int v = (i < RTOT) ? cnt[i] : 0;
  int s = v;
#pragma unroll
  for (int d = 1; d < 64; d <<= 1) {
    int t = __shfl_up(s, d, 64);
    if (lane >= d) s += t;
  }
  int base = 0;
  if (lane == 63) base = atomicAdd(gtot, s);
  base = __shfl(base, 63, 64);
  if (i < RTOT) offs[i] = base + s - v;
}

__global__ void __launch_bounds__(256) fillk(const int* __restrict__ ei, const int* __restrict__ offs,
                                             int* __restrict__ cursor, int* __restrict__ eids) {
  int tid = blockIdx.x * 256 + threadIdx.x;
  if (tid >= Bn*En) return;
  int b = tid / En, e = tid - b*En;
  int tgt = ei[tid*2 + 1];
  int node = b*Nn + tgt;
  int pos = atomicAdd(&cursor[node], 1);
  eids[offs[node] + pos] = e;
}

// ---------- aggregation: half-wave edge parallelism, bf16 outputs ----------
// sumrelB: pre-swizzled row (512B): byte = w*512 + (cb ^ ((w&7)<<4))
// sumsrcB: plain row: byte = w*512 + cb
__global__ void __launch_bounds__(256) aggk(
    const float* __restrict__ nodef, const float* __restrict__ erel,
    const float* __restrict__ emask, const int* __restrict__ ei,
    const int* __restrict__ offs, const int* __restrict__ cnt,
    const int* __restrict__ eids,
    short* __restrict__ sumrelB, short* __restrict__ sumsrcB, float* __restrict__ cntf) {
  int w = (blockIdx.x * 256 + threadIdx.x) >> 6;
  int lane = threadIdx.x & 63;
  if (w >= RTOT) return;
  int b = w / Nn;
  const size_t ebase = (size_t)b * En;
  const size_t nbase = (size_t)b * Nn;
  int s0 = offs[w], kall = cnt[w];
  int h = lane >> 5, l32 = lane & 31;
  float r[8] = {}, a[8] = {};
  float cf = 0.f;
  for (int base = 0; base < kall; base += 64) {
    int k = kall - base; if (k > 64) k = 64;
    int e = 0, sr = 0; float m = 0.f;
    if (lane < k) {
      e  = eids[s0 + base + lane];
      sr = ei[(ebase + e)*2];
      m  = emask[ebase + e];
    }
    for (int j = 0; j < k; j += 2) {
      int je = j + h;
      int e1  = __shfl(e, je, 64);
      int sr1 = __shfl(sr, je, 64);
      float m1 = __shfl(m, je, 64);
      if (je < k) {
        const float* rp = erel  + (ebase + e1)*Dn + l32*8;
        const float* np = nodef + (nbase + sr1)*Dn + l32*8;
        float4 rv0 = *(const float4*)rp;
        float4 rv1 = *(const float4*)(rp + 4);
        float4 nv0 = *(const float4*)np;
        float4 nv1 = *(const float4*)(np + 4);
        r[0]+=rv0.x*m1; r[1]+=rv0.y*m1; r[2]+=rv0.z*m1; r[3]+=rv0.w*m1;
        r[4]+=rv1.x*m1; r[5]+=rv1.y*m1; r[6]+=rv1.z*m1; r[7]+=rv1.w*m1;
        a[0]+=nv0.x*m1; a[1]+=nv0.y*m1; a[2]+=nv0.z*m1; a[3]+=nv0.w*m1;
        a[4]+=nv1.x*m1; a[5]+=nv1.y*m1; a[6]+=nv1.z*m1; a[7]+=nv1.w*m1;
        cf += m1;
      }
    }
  }
#pragma unroll
  for (int i = 0; i < 8; i++) {
    r[i] += __shfl_xor(r[i], 32, 64);
    a[i] += __shfl_xor(a[i], 32, 64);
  }
  cf += __shfl_xor(cf, 32, 64);
  bf16x8 o;
  if (h == 0) {
#pragma unroll
    for (int i = 0; i < 8; i++) o[i] = f2b(r[i]);
    *(bf16x8*)((char*)sumrelB + (size_t)w*512 + ((l32*16) ^ ((w & 7) << 4))) = o;
  } else {
#pragma unroll
    for (int i = 0; i < 8; i++) o[i] = f2b(a[i]);
    *(bf16x8*)((char*)sumsrcB + (size_t)w*512 + l32*16) = o;
  }
  if (lane == 0) cntf[w] = cf;
}

__device__ __forceinline__ bf16x8 ldsA(const char* lds, int r, int kb) {
  int byte = r*512 + (((kb)*2) ^ ((r & 7) << 4));
  return *(const bf16x8*)(lds + byte);
}

// ---------- K3: relln — x = LN(node + (ssrc + sumrel@W + cnt*b)/max(cnt,1)); writes xb (bf16 swz) ----------
__global__ void __launch_bounds__(256, 4) relln(
    const short* __restrict__ sumrelB, const short* __restrict__ relwT,
    const float* __restrict__ relb, const float* __restrict__ nodef,
    const short* __restrict__ sumsrcB, const float* __restrict__ cntf,
    const float* __restrict__ ns, const float* __restrict__ nb,
    short* __restrict__ xb) {
  constexpr int MR = 2;
  __shared__ __align__(16) char lds[16384 + 1024];
  float* red = (float*)(lds + 16384);
  int tid = threadIdx.x;
  int lane = tid & 63, wv = tid >> 6;
  int l15 = lane & 15, l4 = lane >> 4;
  int row0 = blockIdx.x * 32;
  // stage sumrelB via gload_lds (source pre-swizzled, linear copy)
#pragma unroll
  for (int i = 0; i < 4; i++) {
    int u = tid + 256*i;
    int r = u >> 5, wb = (u & 31) * 16;
    gl16((const char*)sumrelB + (size_t)(row0 + r)*512 + wb, lds + u*16);
  }
  __syncthreads();
  f32x4 acc[MR][4] = {};
#pragma unroll
  for (int ks = 0; ks < 8; ks++) {
    bf16x8 af[MR], bfr[4];
#pragma unroll
    for (int m = 0; m < MR; m++) af[m] = ldsA(lds, m*16 + l15, ks*32 + l4*8);
#pragma unroll
    for (int n = 0; n < 4; n++) {
      int col = wv*64 + n*16 + l15;
      bfr[n] = *(const bf16x8*)(relwT + col*Dn + ks*32 + l4*8);
    }
#pragma unroll
    for (int m = 0; m < MR; m++)
#pragma unroll
      for (int n = 0; n < 4; n++)
        acc[m][n] = __builtin_amdgcn_mfma_f32_16x16x32_bf16(af[m], bfr[n], acc[m][n], 0, 0, 0);
  }
  int cols[4]; float rb_c[4], ns_c[4], nb_c[4];
#pragma unroll
  for (int n = 0; n < 4; n++) {
    cols[n] = wv*64 + n*16 + l15;
    rb_c[n] = relb[cols[n]]; ns_c[n] = ns[cols[n]]; nb_c[n] = nb[cols[n]];
  }
  // epilogue + LN
  float s1[MR][4], s2[MR][4];
#pragma unroll
  for (int m = 0; m < MR; m++)
#pragma unroll
    for (int g = 0; g < 4; g++) {
      int r = m*16 + l4*4 + g; int rg = row0 + r;
      float cf  = cntf[rg];
      float inv = 1.0f / fmaxf(cf, 1.0f);
      float aa = 0.f, qq = 0.f;
#pragma unroll
      for (int n = 0; n < 4; n++) {
        float ssrc = b2f(*(const unsigned short*)((const char*)sumsrcB + (size_t)rg*512 + cols[n]*2));
        float nfv  = nodef[(size_t)rg*Dn + cols[n]];
        float vv = nfv + (ssrc + acc[m][n][g] + cf*rb_c[n]) * inv;
        acc[m][n][g] = vv;
        aa += vv; qq += vv*vv;
      }
#pragma unroll
      for (int d = 1; d < 16; d <<= 1) { aa += __shfl_xor(aa, d, 16); qq += __shfl_xor(qq, d, 16); }
      s1[m][g] = aa; s2[m][g] = qq;
    }
  if (l15 == 0) {
#pragma unroll
    for (int m = 0; m < MR; m++)
#pragma unroll
      for (int g = 0; g < 4; g++) {
        int r = m*16 + l4*4 + g;
        red[(wv*32 + r)*2]     = s1[m][g];
        red[(wv*32 + r)*2 + 1] = s2[m][g];
      }
  }
  __syncthreads();
#pragma unroll
  for (int m = 0; m < MR; m++)
#pragma unroll
    for (int g = 0; g < 4; g++) {
      int r = m*16 + l4*4 + g; int rg = row0 + r;
      float t1 = 0.f, t2 = 0.f;
#pragma unroll
      for (int u = 0; u < 4; u++) { t1 += red[(u*32 + r)*2]; t2 += red[(u*32 + r)*2 + 1]; }
      float mean = t1 * (1.0f/Dn);
      float var  = t2 * (1.0f/Dn) - mean*mean;
      float rstd = rsqrtf(var + 1e-5f);
#pragma unroll
      for (int n = 0; n < 4; n++) {
        float xv = (acc[m][n][g] - mean)*rstd*ns_c[n] + nb_c[n];
        *(short*)((char*)xb + (size_t)rg*512 + ((cols[n]*2) ^ ((rg & 7) << 4))) = f2b(xv);
      }
    }
}

// ---------- FFN GEMM1: H = gelu(x @ w1 + b1), full batch, m97-shape ----------
// H pre-swizzled: byte = r*2048 + (c>>6)*128 + (((c&63)*2) ^ ((r&7)<<4))
__global__ void __launch_bounds__(256) ffn1k(
    const short* __restrict__ xb, const short* __restrict__ w1s,
    const float* __restrict__ b1, short* __restrict__ H) {
  __shared__ __align__(16) char lds[32768];
  char* Xa = lds;            // [128 r][128B]
  char* Wa = lds + 16384;    // [128 c][128B]
  int tid = threadIdx.x;
  int lane = tid & 63, wv = tid >> 6;
  int l15 = lane & 15, l4 = lane >> 4;
  int wm = wv >> 1, wn = wv & 1;       // 2m x 2n waves, 64x64 each
  int row0 = blockIdx.x * 128;
  int col0 = blockIdx.y * 128;

  f32x4 acc[4][4] = {};
#pragma unroll 1
  for (int kk = 0; kk < 4; kk++) {
    // A: xb pre-swizzled, linear chunk copy
#pragma unroll
    for (int i = 0; i < 4; i++) {
      int u = tid + 256*i;
      int r = u >> 3, wb = (u & 7) * 16;
      int gr = row0 + r; if (gr > RTOT - 1) gr = RTOT - 1;
      gl16((const char*)xb + (size_t)gr*512 + kk*128 + wb, Xa + u*16);
    }
    // B: w1s pre-swizzled, linear copy
#pragma unroll
    for (int i = 0; i < 4; i++) {
      int u = tid + 256*i;
      gl16((const char*)w1s + (size_t)kk*131072 + col0*128 + u*16, Wa + u*16);
    }
    __syncthreads();
#pragma unroll
    for (int ksl = 0; ksl < 2; ksl++) {
      int kb2 = (ksl*32 + l4*8) * 2;
      bf16x8 af[4], bw[4];
#pragma unroll
      for (int mf = 0; mf < 4; mf++) {
        int r = wm*64 + mf*16 + l15;
        af[mf] = *(const bf16x8*)(Xa + r*128 + (kb2 ^ ((r & 7) << 4)));
      }
#pragma unroll
      for (int nf = 0; nf < 4; nf++) {
        int c = wn*64 + nf*16 + l15;
        bw[nf] = *(const bf16x8*)(Wa + c*128 + (kb2 ^ ((c & 7) << 4)));
      }
#pragma unroll
      for (int mf = 0; mf < 4; mf++)
#pragma unroll
        for (int nf = 0; nf < 4; nf++)
          acc[mf][nf] = __builtin_amdgcn_mfma_f32_16x16x32_bf16(af[mf], bw[nf], acc[mf][nf], 0, 0, 0);
    }
    __syncthreads();
  }
  // epilogue: bias + gelu -> LDS [128][256B swz] -> 16B H stores
  float b1v[4];
#pragma unroll
  for (int nf = 0; nf < 4; nf++) b1v[nf] = b1[col0 + wn*64 + nf*16 + l15];
#pragma unroll
  for (int mf = 0; mf < 4; mf++)
#pragma unroll
    for (int g = 0; g < 4; g++) {
      int R = wm*64 + mf*16 + l4*4 + g;
#pragma unroll
      for (int nf = 0; nf < 4; nf++) {
        int C = wn*64 + nf*16 + l15;
        float hv = gelu_f(acc[mf][nf][g] + b1v[nf]);
        *(short*)(lds + R*256 + ((C*2) ^ ((R & 7) << 4))) = f2b(hv);
      }
    }
  __syncthreads();
#pragma unroll
  for (int i = 0; i < 8; i++) {
    int u = tid + 256*i;
    int r = u >> 4, c = (u & 15) * 8;
    int gr = row0 + r;
    if (gr >= RTOT) continue;
    bf16x8 v = *(const bf16x8*)(lds + r*256 + ((c*2) ^ ((r & 7) << 4)));
    int gc = col0 + c;
    size_t hb = (size_t)gr*2048 + (gc >> 6)*128 + (((gc & 63)*2) ^ ((gr & 7) << 4));
    *(bf16x8*)((char*)H + hb) = v;
  }
}

// ---------- FFN GEMM2: out = LN(x + H @ w2 + b2), full batch ----------
__global__ void __launch_bounds__(512, 4) ffn2k(
    const short* __restrict__ H, const short* __restrict__ w2s,
    const float* __restrict__ b2, const float* __restrict__ fs,
    const float* __restrict__ fb, const short* __restrict__ xb,
    float* __restrict__ out) {
  __shared__ __align__(16) char lds[8192 + 32768];
  char* Ha  = lds;            // 64 r x 128B
  char* W2a = lds + 8192;     // 256 c x 128B
  float* red = (float*)lds;   // aliases Ha after loop
  int tid = threadIdx.x;
  int lane = tid & 63, wv = tid >> 6;
  int l15 = lane & 15, l4 = lane >> 4;
  int wm = wv >> 2, wn = wv & 3;
  int rows0 = blockIdx.x * 64;

  f32x4 acc[2][4] = {};
#pragma unroll 1
  for (int kk = 0; kk < 16; kk++) {
    {
      int flat = wv*1024 + lane*16;
      int r = flat >> 7, bo = flat & 127;
      int lr = rows0 + r; if (lr > RTOT - 1) lr = RTOT - 1;
      gl16((const char*)H + (size_t)lr*2048 + kk*128 + bo, Ha + flat);
    }
#pragma unroll
    for (int i = 0; i < 4; i++) {
      int base = wv*4096 + i*1024;
      gl16((const char*)w2s + (size_t)kk*32768 + base + lane*16, W2a + base + lane*16);
    }
    __syncthreads();
#pragma unroll
    for (int ksl = 0; ksl < 2; ksl++) {
      bf16x8 ah[2], bw[4];
#pragma unroll
      for (int mf = 0; mf < 2; mf++) {
        int r = wm*32 + mf*16 + l15;
        ah[mf] = *(const bf16x8*)(Ha + r*128 + (((ksl*32 + l4*8)*2) ^ ((r & 7) << 4)));
      }
#pragma unroll
      for (int nf = 0; nf < 4; nf++) {
        int c = wn*64 + nf*16 + l15;
        bw[nf] = *(const bf16x8*)(W2a + c*128 + (((ksl*32 + l4*8)*2) ^ ((c & 7) << 4)));
      }
#pragma unroll
      for (int mf = 0; mf < 2; mf++)
#pragma unroll
        for (int nf = 0; nf < 4; nf++)
          acc[mf][nf] = __builtin_amdgcn_mfma_f32_16x16x32_bf16(ah[mf], bw[nf], acc[mf][nf], 0, 0, 0);
    }
    __syncthreads();
  }
  // epilogue: + b2 + residual xb (bf16), LayerNorm over 256 cols
  float b2c[4], fsc[4], fbc[4];
#pragma unroll
  for (int nf = 0; nf < 4; nf++) {
    int col = wn*64 + nf*16 + l15;
    b2c[nf] = b2[col]; fsc[nf] = fs[col]; fbc[nf] = fb[col];
  }
#pragma unroll
  for (int mf = 0; mf < 2; mf++)
#pragma unroll
    for (int g = 0; g < 4; g++) {
      int R = wm*32 + mf*16 + l4*4 + g;
      int gr = rows0 + R;
      bool ok = gr < RTOT;
      float a = 0.f, q = 0.f;
#pragma unroll
      for (int nf = 0; nf < 4; nf++) {
        int col = wn*64 + nf*16 + l15;
        float xv = 0.f;
        if (ok) xv = b2f(*(const unsigned short*)((const char*)xb + (size_t)gr*512 + ((col*2) ^ ((gr & 7) << 4))));
        float vv = xv + acc[mf][nf][g] + b2c[nf];
        acc[mf][nf][g] = vv;
        a += vv; q += vv*vv;
      }
#pragma unroll
      for (int d = 1; d < 16; d <<= 1) { a += __shfl_xor(a, d, 16); q += __shfl_xor(q, d, 16); }
      if (l15 == 0) {
        red[(wn*64 + R)*2]     = a;
        red[(wn*64 + R)*2 + 1] = q;
      }
    }
  __syncthreads();
#pragma unroll
  for (int mf = 0; mf < 2; mf++)
#pragma unroll
    for (int g = 0; g < 4; g++) {
      int R = wm*32 + mf*16 + l4*4 + g;
      int gr = rows0 + R;
      if (gr >= RTOT) continue;
      float t1 = 0.f, t2 = 0.f;
#pragma unroll
      for (int u = 0; u < 4; u++) { t1 += red[(u*64 + R)*2]; t2 += red[(u*64 + R)*2 + 1]; }
      float mean = t1 * (1.0f/Dn);
      float var  = t2 * (1.0f/Dn) - mean*mean;
      float rstd = rsqrtf(var + 1e-5f);
#pragma unroll
      for (int nf = 0; nf < 4; nf++) {
        int col = wn*64 + nf*16 + l15;
        out[(size_t)gr*Dn + col] = (acc[mf][nf][g] - mean)*rstd*fsc[nf] + fbc[nf];
      }
    }
}

// ---------- host ----------
extern "C" void kernel_launch(void* const* d_in, const int* in_sizes, int n_in,
                              void* d_out, int out_size, void* d_ws, size_t ws_size,
                              hipStream_t stream) {
  const float* nodef = (const float*)d_in[0];
  const float* erel  = (const float*)d_in[1];
  const float* emask = (const float*)d_in[2];
  const float* relw  = (const float*)d_in[3];
  const float* relb  = (const float*)d_in[4];
  const float* ns    = (const float*)d_in[5];
  const float* nb    = (const float*)d_in[6];
  const float* w1    = (const float*)d_in[7];
  const float* b1    = (const float*)d_in[8];
  const float* w2    = (const float*)d_in[9];
  const float* b2    = (const float*)d_in[10];
  const float* fs    = (const float*)d_in[11];
  const float* fb    = (const float*)d_in[12];
  const int*   ei    = (const int*)d_in[13];
  float* out = (float*)d_out;
  char* ws = (char*)d_ws;

  constexpr size_t SZ_ROWB = (size_t)RTOT * Dn * 2;       // 51.2 MB bf16 array
  constexpr size_t O_SRB = 0;
  constexpr size_t O_SSB = O_SRB + SZ_ROWB;
  constexpr size_t O_XB  = O_SSB + SZ_ROWB;
  constexpr size_t O_H   = O_XB + SZ_ROWB;
  constexpr size_t O_CNT = O_H + (size_t)RTOT * Hn * 2;   // H = 204.8 MB
  constexpr size_t O_CUR = O_CNT + (size_t)RTOT*4;
  constexpr size_t O_OFF = O_CUR + (size_t)RTOT*4;
  constexpr size_t O_EID = O_OFF + ((size_t)(RTOT+1)*4 + 124);
  constexpr size_t O_CNTF = O_EID + (size_t)Bn*En*4;
  constexpr size_t O_RWT = O_CNTF + (size_t)RTOT*4;
  constexpr size_t O_W1T = O_RWT + (size_t)Dn*Dn*2;
  constexpr size_t O_W2T = O_W1T + (size_t)Dn*Hn*2;
  constexpr size_t WS_NEED = O_W2T + (size_t)Hn*Dn*2;     // ~366 MB
  if (ws_size < WS_NEED) return;

  short* sumrelB = (short*)(ws + O_SRB);
  short* sumsrcB = (short*)(ws + O_SSB);
  short* xb      = (short*)(ws + O_XB);
  short* Hbuf    = (short*)(ws + O_H);
  int*   cnt    = (int*)(ws + O_CNT);
  int*   cursor = (int*)(ws + O_CUR);
  int*   offs   = (int*)(ws + O_OFF);
  int*   eids   = (int*)(ws + O_EID);
  float* cntf   = (float*)(ws + O_CNTF);
  short* relwT  = (short*)(ws + O_RWT);
  short* w1s    = (short*)(ws + O_W1T);
  short* w2s    = (short*)(ws + O_W2T);
  int*   gtot   = offs + RTOT;

  hipMemsetAsync(ws + O_CNT, 0, O_EID - O_CNT, stream);

  wconv<<<(Dn*Dn + Dn*Hn + Hn*Dn + 255) / 256, 256, 0, stream>>>(relw, w1, w2, relwT, w1s, w2s);
  histk<<<(Bn*En) / 256, 256, 0, stream>>>(ei, cnt);
  offsk<<<(RTOT + 255) / 256, 256, 0, stream>>>(cnt, offs, gtot);
  fillk<<<(Bn*En) / 256, 256, 0, stream>>>(ei, offs, cursor, eids);
  aggk<<<(RTOT + 3) / 4, 256, 0, stream>>>(nodef, erel, emask, ei, offs, cnt, eids,
                                           sumrelB, sumsrcB, cntf);
  relln<<<RTOT / 32, 256, 0, stream>>>(sumrelB, relwT, relb, nodef, sumsrcB, cntf, ns, nb, xb);
  ffn1k<<<dim3((RTOT + 127) / 128, Hn / 128), 256, 0, stream>>>(xb, w1s, b1, Hbuf);
  ffn2k<<<(RTOT + 63) / 64, 512, 0, stream>>>(Hbuf, w2s, b2, fs, fb, xb, out);
}